// Round 3
// baseline (139.408 us; speedup 1.0000x reference)
//
#include <hip/hip_runtime.h>
#include <hip/hip_bf16.h>

// MMD-RBF: B=4, Ns=Nt=2048 (N=4096 concat), K=32, KERNEL_MUL=2, KERNEL_NUM=5.
// Pass 1: per-point sq-norms + per-batch {sum_sq, component sums} (bw via Gram identity)
// Pass 2: bandwidth coefficients  nc_t = -log2(e)/(bw*2^t)
// Pass 3: upper-tri 64x64 tile pairs (bx<=by via early-exit 2D grid);
//         off-diag tiles counted into both (q, qT) quadrants (kernel symmetry);
//         f64 spread accumulators per (batch, quadrant)
// Pass 4: out[b] = (XX + YY - XY - YX) / 2048^2

#define NPTS 4096   // per batch (2048 src + 2048 tgt)
#define HALF 2048
#define KDIM 32
#define TILE 64
#define NTB  64     // NPTS / TILE
#define SPREAD 64

__device__ __forceinline__ float fast_exp2(float x) {
#if __has_builtin(__builtin_amdgcn_exp2f)
  return __builtin_amdgcn_exp2f(x);
#else
  return exp2f(x);
#endif
}

__device__ __forceinline__ const float* point_ptr(const float* __restrict__ src,
                                                  const float* __restrict__ tgt,
                                                  int b, int p) {
  return (p < HALF) ? src + ((size_t)b * HALF + p) * KDIM
                    : tgt + ((size_t)b * HALF + (p - HALF)) * KDIM;
}

// ---------------- Pass 1: sq per point, and per-batch {sum_sq, s_vec[32]} ----
__global__ void mmd_pass1(const float* __restrict__ src, const float* __restrict__ tgt,
                          float* __restrict__ sqArr, double* __restrict__ sums) {
  const int b = blockIdx.y;
  const int p = blockIdx.x * 256 + threadIdx.x;
  const float* __restrict__ xp = point_ptr(src, tgt, b, p);

  float x[KDIM];
#pragma unroll
  for (int q = 0; q < 8; ++q) {
    float4 v = reinterpret_cast<const float4*>(xp)[q];
    x[4*q+0] = v.x; x[4*q+1] = v.y; x[4*q+2] = v.z; x[4*q+3] = v.w;
  }
  float s0 = 0.f, s1 = 0.f, s2 = 0.f, s3 = 0.f;
#pragma unroll
  for (int q = 0; q < 8; ++q) {
    s0 = fmaf(x[4*q+0], x[4*q+0], s0);
    s1 = fmaf(x[4*q+1], x[4*q+1], s1);
    s2 = fmaf(x[4*q+2], x[4*q+2], s2);
    s3 = fmaf(x[4*q+3], x[4*q+3], s3);
  }
  float sq = (s0 + s1) + (s2 + s3);
  sqArr[(size_t)b * NPTS + p] = sq;

  __shared__ float lx[256][KDIM + 1];   // +1 pad: column reads conflict-free
  __shared__ float part[8][KDIM];
  __shared__ float sqpart[4];

#pragma unroll
  for (int k = 0; k < KDIM; ++k) lx[threadIdx.x][k] = x[k];

  // wave (64) reduce of sq
  float w = sq;
#pragma unroll
  for (int off = 32; off > 0; off >>= 1) w += __shfl_down(w, off, 64);
  if ((threadIdx.x & 63) == 0) sqpart[threadIdx.x >> 6] = w;
  __syncthreads();

  // component sums: thread t sums component (t&31) over rows [g*32, g*32+32)
  const int k = threadIdx.x & 31, g = threadIdx.x >> 5;
  float ps = 0.f;
#pragma unroll 8
  for (int r = 0; r < 32; ++r) ps += lx[g * 32 + r][k];
  part[g][k] = ps;
  __syncthreads();

  if (threadIdx.x < 32) {
    float tot = 0.f;
#pragma unroll
    for (int gg = 0; gg < 8; ++gg) tot += part[gg][threadIdx.x];
    atomicAdd(&sums[b * 33 + 1 + threadIdx.x], (double)tot);
  }
  if (threadIdx.x == 63) {
    float t = sqpart[0] + sqpart[1] + sqpart[2] + sqpart[3];
    atomicAdd(&sums[b * 33 + 0], (double)t);
  }
}

// ---------------- Pass 2: bandwidth coefficients ----------------------------
__global__ void mmd_pass2(const double* __restrict__ sums, float* __restrict__ coef) {
  const int b = threadIdx.x;
  if (b >= 4) return;
  double ssq = sums[b * 33 + 0];
  double s2 = 0.0;
  for (int kk = 0; kk < KDIM; ++kk) {
    double v = sums[b * 33 + 1 + kk];
    s2 += v * v;
  }
  const double N = (double)NPTS;
  double sumL2 = 2.0 * N * ssq - 2.0 * s2;
  double bw = sumL2 / (N * N - N + 1e-8);
  bw *= 0.25;  // / KERNEL_MUL^(KERNEL_NUM/2) = / 4
  const double LOG2E = 1.4426950408889634;
  for (int t = 0; t < 5; ++t)
    coef[b * 8 + t] = (float)(-LOG2E / (bw * (double)(1 << t)));
}

// ---------------- Pass 3: upper-tri tile pairs, symmetry-doubled ------------
__global__ void __launch_bounds__(64)
mmd_pass3(const float* __restrict__ src, const float* __restrict__ tgt,
          const float* __restrict__ sqArr, const float* __restrict__ coef,
          double* __restrict__ quadbuf) {
  const int bx = blockIdx.x;
  const int by = blockIdx.y;
  if (bx > by) return;                 // upper triangle only (symmetry)
  const int b = blockIdx.z;

  const int lane = threadIdx.x;
  const int row = bx * TILE + lane;
  const int col0 = by * TILE;

  const float* __restrict__ rp = point_ptr(src, tgt, b, row);
  float r[KDIM];
#pragma unroll
  for (int q = 0; q < 8; ++q) {
    float4 v = reinterpret_cast<const float4*>(rp)[q];
    r[4*q+0] = v.x; r[4*q+1] = v.y; r[4*q+2] = v.z; r[4*q+3] = v.w;
  }
  const float sq_i = sqArr[(size_t)b * NPTS + row];
  const float nc0 = coef[b * 8 + 0];
  const float nc1 = coef[b * 8 + 1];
  const float nc2 = coef[b * 8 + 2];
  const float nc3 = coef[b * 8 + 3];
  const float nc4 = coef[b * 8 + 4];
  const float eps2 = 1.4426950e-8f;  // 1e-8 * log2(e)

  const float* __restrict__ cbase = point_ptr(src, tgt, b, col0);
  const float* __restrict__ sqc = sqArr + (size_t)b * NPTS + col0;

  double acc = 0.0;
  for (int jc = 0; jc < 8; ++jc) {
    float partf = 0.f;
#pragma unroll 2
    for (int jj = 0; jj < 8; ++jj) {
      const int j = jc * 8 + jj;
      const float4* __restrict__ cp4 =
          reinterpret_cast<const float4*>(cbase + (size_t)j * KDIM);
      const float sq_j = sqc[j];
      float d0 = 0.f, d1 = 0.f, d2 = 0.f, d3 = 0.f;
#pragma unroll
      for (int q = 0; q < 8; ++q) {
        float4 cv = cp4[q];
        d0 = fmaf(r[4*q+0], cv.x, d0);
        d1 = fmaf(r[4*q+1], cv.y, d1);
        d2 = fmaf(r[4*q+2], cv.z, d2);
        d3 = fmaf(r[4*q+3], cv.w, d3);
      }
      const float dot = (d0 + d1) + (d2 + d3);
      const float L2 = fmaf(-2.0f, dot, sq_i + sq_j);
      float ks = fast_exp2(fmaf(L2, nc0, eps2));
      ks += fast_exp2(fmaf(L2, nc1, eps2));
      ks += fast_exp2(fmaf(L2, nc2, eps2));
      ks += fast_exp2(fmaf(L2, nc3, eps2));
      ks += fast_exp2(fmaf(L2, nc4, eps2));
      partf += ks;
    }
    acc += (double)partf;
  }

  // wave reduce (single wave per block)
#pragma unroll
  for (int off = 32; off > 0; off >>= 1) acc += __shfl_down(acc, off, 64);

  if (lane == 0) {
    const int rh = (bx >= 32) ? 1 : 0;   // row half (0=X, 1=Y)
    const int ch = (by >= 32) ? 1 : 0;   // col half
    const int q  = (rh << 1) | ch;
    const int qT = (ch << 1) | rh;
    const int slot = (bx + by * NTB) & (SPREAD - 1);
    atomicAdd(&quadbuf[(((b << 2) | q) * SPREAD) + slot], acc);
    if (bx != by)
      atomicAdd(&quadbuf[(((b << 2) | qT) * SPREAD) + slot], acc);
  }
}

// ---------------- Pass 4: final combine -------------------------------------
__global__ void mmd_pass4(const double* __restrict__ quadbuf, float* __restrict__ out) {
  const int b = threadIdx.x;
  if (b < 4) {
    double q[4];
#pragma unroll
    for (int qq = 0; qq < 4; ++qq) {
      double s = 0.0;
      for (int i = 0; i < SPREAD; ++i) s += quadbuf[((b << 2) | qq) * SPREAD + i];
      q[qq] = s;
    }
    const double inv = 1.0 / ((double)HALF * (double)HALF);
    out[b] = (float)((q[0] + q[3] - q[1] - q[2]) * inv);
  }
}

extern "C" void kernel_launch(void* const* d_in, const int* in_sizes, int n_in,
                              void* d_out, int out_size, void* d_ws, size_t ws_size,
                              hipStream_t stream) {
  const float* src = (const float*)d_in[0];
  const float* tgt = (const float*)d_in[1];
  float* out = (float*)d_out;

  char* ws = (char*)d_ws;
  float*  sqArr   = (float*)ws;                         // 4*4096*4       = 65536 B
  double* sums    = (double*)(ws + 65536);              // 4*33*8         = 1056 B
  double* quadbuf = (double*)(ws + 65536 + 1056);       // 4*4*64*8       = 8192 B
  float*  coef    = (float*)(ws + 65536 + 1056 + 8192); // 4*8*4          = 128 B

  // zero the accumulator region (sums + quadbuf)
  hipMemsetAsync(ws + 65536, 0, 1056 + 8192, stream);

  mmd_pass1<<<dim3(NPTS / 256, 4), 256, 0, stream>>>(src, tgt, sqArr, sums);
  mmd_pass2<<<1, 64, 0, stream>>>(sums, coef);
  mmd_pass3<<<dim3(NTB, NTB, 4), TILE, 0, stream>>>(src, tgt, sqArr, coef, quadbuf);
  mmd_pass4<<<1, 64, 0, stream>>>(quadbuf, out);
}